// Round 12
// baseline (253.812 us; speedup 1.0000x reference)
//
#include <hip/hip_runtime.h>

#define N_NODES 100000
#define N_EDGES 3200000
#define FEAT 64
#define N_GRAPHS 64

#define BKT_SHIFT 8
#define BKT_SIZE  256                       // nodes per bucket
#define NBKT      391                       // ceil(N_NODES / 256)
#define BKT_PAD   8960                      // mean 8184, sd 90 -> mean + 8.6 sigma
#define E4        (N_EDGES / 4)             // 800000 int4 chunks
#define GEMM1_BLKS ((N_NODES + 63) / 64)    // 1563

__device__ __forceinline__ ushort f2bf(float f) {      // round-to-nearest-even
    unsigned u = __float_as_uint(f);
    return (ushort)((u + 0x7fffu + ((u >> 16) & 1u)) >> 16);
}
__device__ __forceinline__ float bf2f(ushort s) {
    return __uint_as_float(((unsigned)s) << 16);
}

// accumulate 8 bf16 features (one uint4) with weight w
__device__ __forceinline__ void acc8(float* a, uint4 v, float w) {
    a[0] = fmaf(__uint_as_float(v.x << 16),         w, a[0]);
    a[1] = fmaf(__uint_as_float(v.x & 0xffff0000u), w, a[1]);
    a[2] = fmaf(__uint_as_float(v.y << 16),         w, a[2]);
    a[3] = fmaf(__uint_as_float(v.y & 0xffff0000u), w, a[3]);
    a[4] = fmaf(__uint_as_float(v.z << 16),         w, a[4]);
    a[5] = fmaf(__uint_as_float(v.z & 0xffff0000u), w, a[5]);
    a[6] = fmaf(__uint_as_float(v.w << 16),         w, a[6]);
    a[7] = fmaf(__uint_as_float(v.w & 0xffff0000u), w, a[7]);
}

// ---------------------------------------------------------------- zero
__global__ void k_zero(int* __restrict__ bcnt, float* __restrict__ pool, int* __restrict__ offs) {
    int i = blockIdx.x * blockDim.x + threadIdx.x;
    if (i < NBKT) bcnt[i] = 0;
    if (i < N_GRAPHS * FEAT + N_GRAPHS) pool[i] = 0.0f;
    if (i == 0) offs[N_NODES] = N_EDGES;
}

// ---------------------------------------------------------------- fused: bucket (blocks 0..195) | gemm1 (rest)
__global__ void __launch_bounds__(1024) k_pre(const int* __restrict__ row,
                                              const int* __restrict__ col,
                                              int* __restrict__ bcnt,
                                              int* __restrict__ tmp,
                                              const float* __restrict__ x,
                                              const float* __restrict__ W1,
                                              ushort* __restrict__ hbf) {
    __shared__ int lcnt0[NBKT];
    __shared__ int lcnt1[NBKT];             // 2x replicated histogram halves contention
    __shared__ float Ws[64][64];
    __shared__ float At[64][68];
    int tid = threadIdx.x;

    if (blockIdx.x < 196) {
        // ---------------- bucket path ----------------
        int* lc = (tid >= 512) ? lcnt1 : lcnt0;
        if (tid < NBKT) { lcnt0[tid] = 0; lcnt1[tid] = 0; }
        __syncthreads();
        int base = blockIdx.x * 4096;           // int4 units; 16 edges/thread
        int4 c[4];
        #pragma unroll
        for (int k = 0; k < 4; ++k) {
            int t4 = base + k * 1024 + tid;
            if (t4 < E4) {
                c[k] = ((const int4*)col)[t4];
                atomicAdd(&lc[c[k].x >> BKT_SHIFT], 1);
                atomicAdd(&lc[c[k].y >> BKT_SHIFT], 1);
                atomicAdd(&lc[c[k].z >> BKT_SHIFT], 1);
                atomicAdd(&lc[c[k].w >> BKT_SHIFT], 1);
            }
        }
        __syncthreads();
        if (tid < NBKT) {
            int l0 = lcnt0[tid], l1 = lcnt1[tid];
            int bse = atomicAdd(&bcnt[tid], l0 + l1);
            lcnt0[tid] = bse;               // cursor for copy 0
            lcnt1[tid] = bse + l0;          // cursor for copy 1
        }
        __syncthreads();
        #pragma unroll
        for (int k = 0; k < 4; ++k) {
            int t4 = base + k * 1024 + tid;
            if (t4 < E4) {
                int4 r = ((const int4*)row)[t4];
                int b0 = c[k].x >> BKT_SHIFT, b1 = c[k].y >> BKT_SHIFT;
                int b2 = c[k].z >> BKT_SHIFT, b3 = c[k].w >> BKT_SHIFT;
                int s0 = atomicAdd(&lc[b0], 1);
                int s1 = atomicAdd(&lc[b1], 1);
                int s2 = atomicAdd(&lc[b2], 1);
                int s3 = atomicAdd(&lc[b3], 1);
                if (s0 < BKT_PAD) tmp[b0 * BKT_PAD + s0] = (r.x << BKT_SHIFT) | (c[k].x & (BKT_SIZE - 1));
                if (s1 < BKT_PAD) tmp[b1 * BKT_PAD + s1] = (r.y << BKT_SHIFT) | (c[k].y & (BKT_SIZE - 1));
                if (s2 < BKT_PAD) tmp[b2 * BKT_PAD + s2] = (r.z << BKT_SHIFT) | (c[k].z & (BKT_SIZE - 1));
                if (s3 < BKT_PAD) tmp[b3 * BKT_PAD + s3] = (r.w << BKT_SHIFT) | (c[k].w & (BKT_SIZE - 1));
            }
        }
    } else {
        // ---------------- gemm1 path: h = x @ W1 (UNSCALED; dinv folded into gather) ----------------
        int row0 = (blockIdx.x - 196) * 64;
        {
            float4 v = ((const float4*)W1)[tid];
            *(float4*)&Ws[tid >> 4][(tid & 15) * 4] = v;
        }
        {
            int r = tid >> 4, f4 = tid & 15;
            int grow = row0 + r;
            float4 v = make_float4(0.f, 0.f, 0.f, 0.f);
            if (grow < N_NODES) v = ((const float4*)(x + (size_t)grow * FEAT))[f4];
            int k = f4 * 4;
            At[k][r] = v.x; At[k + 1][r] = v.y; At[k + 2][r] = v.z; At[k + 3][r] = v.w;
        }
        __syncthreads();
        int tx = tid & 31, ty = tid >> 5;       // 32x32 threads; 2x2 each
        float a00 = 0.f, a01 = 0.f, a10 = 0.f, a11 = 0.f;
        #pragma unroll 8
        for (int k = 0; k < 64; ++k) {
            float2 wv = *(const float2*)&Ws[k][tx * 2];
            float2 av = *(const float2*)&At[k][ty * 2];
            a00 = fmaf(av.x, wv.x, a00); a01 = fmaf(av.x, wv.y, a01);
            a10 = fmaf(av.y, wv.x, a10); a11 = fmaf(av.y, wv.y, a11);
        }
        int r0 = row0 + ty * 2;
        if (r0 < N_NODES)
            *(unsigned*)(hbf + (size_t)r0 * FEAT + tx * 2) =
                (unsigned)f2bf(a00) | ((unsigned)f2bf(a01) << 16);
        if (r0 + 1 < N_NODES)
            *(unsigned*)(hbf + (size_t)(r0 + 1) * FEAT + tx * 2) =
                (unsigned)f2bf(a10) | ((unsigned)f2bf(a11) << 16);
    }
}

// ---------------------------------------------------------------- per-bucket CSR build (register-staged)
__global__ void __launch_bounds__(1024) k_build(const int* __restrict__ tmp,
                                                const int* __restrict__ bcnt,
                                                int* __restrict__ offs,
                                                float* __restrict__ dinv,
                                                int* __restrict__ csr_row) {
    __shared__ int hist[BKT_SIZE];
    __shared__ int wpart[4];
    __shared__ int sh_start;
    int b = blockIdx.x, tid = threadIdx.x;

    if (tid < 64) {
        int sum = 0;
        for (int c = 0; c < NBKT; c += 64) {
            int idx = c + tid;
            int v = (idx < b) ? bcnt[idx] : 0;
            #pragma unroll
            for (int d2 = 1; d2 < 64; d2 <<= 1) v += __shfl_xor(v, d2);
            sum += v;
        }
        if (tid == 0) sh_start = sum;
    }
    if (tid < BKT_SIZE) hist[tid] = 0;
    __syncthreads();
    int s = sh_start;
    int count = min(bcnt[b], BKT_PAD);
    const int* seg = tmp + (size_t)b * BKT_PAD;

    int e[9];
    #pragma unroll
    for (int k = 0; k < 9; ++k) {
        int idx = k * 1024 + tid;
        e[k] = -1;
        if (idx < count) {
            e[k] = seg[idx];
            atomicAdd(&hist[e[k] & (BKT_SIZE - 1)], 1);
        }
    }
    __syncthreads();

    int cnt_n = 0, p = 0;
    if (tid < BKT_SIZE) {
        cnt_n = hist[tid];
        p = cnt_n;
        #pragma unroll
        for (int d = 1; d < 64; d <<= 1) {
            int t2 = __shfl_up(p, d);
            if ((tid & 63) >= d) p += t2;
        }
        if ((tid & 63) == 63) wpart[tid >> 6] = p;
    }
    __syncthreads();
    if (tid == 0) {
        int run = 0;
        #pragma unroll
        for (int w = 0; w < 4; ++w) { int t2 = wpart[w]; wpart[w] = run; run += t2; }
    }
    __syncthreads();
    if (tid < BKT_SIZE) {
        int excl = wpart[tid >> 6] + p - cnt_n;
        int node = (b << BKT_SHIFT) + tid;
        if (node < N_NODES) {
            offs[node] = s + excl;
            dinv[node] = rsqrtf((float)(cnt_n + 1));   // +1 self-loop
        }
        hist[tid] = s + excl;                           // reuse as cursor
    }
    __syncthreads();

    #pragma unroll
    for (int k = 0; k < 9; ++k) {
        if (e[k] >= 0) {
            int slot = atomicAdd(&hist[e[k] & (BKT_SIZE - 1)], 1);
            csr_row[slot] = e[k] >> BKT_SHIFT;
        }
    }
}

// ---------------------------------------------------------------- tiled GEMM layer2: bf16 agg in, relu(in+bias)
__global__ void __launch_bounds__(256, 4) k_gemm2(const ushort* __restrict__ in,
                                                  const float* __restrict__ W,
                                                  const float* __restrict__ bias,
                                                  const float* __restrict__ dinv,
                                                  ushort* __restrict__ out) {
    __shared__ float Ws[64][64];
    __shared__ float At[64][68];
    int tid = threadIdx.x;
    int row0 = blockIdx.x * 64;

    const float4* Wv = (const float4*)W;
    #pragma unroll
    for (int i = 0; i < 4; ++i) {
        int idx = tid + i * 256;
        float4 v = Wv[idx];
        *(float4*)&Ws[idx >> 4][(idx & 15) * 4] = v;
    }
    #pragma unroll
    for (int i = 0; i < 2; ++i) {
        int idx = tid + i * 256;            // uint4 index (8 bf16), 512 total
        int r = idx >> 3, q = idx & 7;
        int grow = row0 + r;
        uint4 v = make_uint4(0u, 0u, 0u, 0u);
        if (grow < N_NODES) v = ((const uint4*)(in + (size_t)grow * FEAT))[q];
        float4 b0 = ((const float4*)bias)[q * 2];
        float4 b1 = ((const float4*)bias)[q * 2 + 1];
        int k = q * 8;
        At[k + 0][r] = fmaxf(__uint_as_float(v.x << 16)          + b0.x, 0.f);
        At[k + 1][r] = fmaxf(__uint_as_float(v.x & 0xffff0000u)  + b0.y, 0.f);
        At[k + 2][r] = fmaxf(__uint_as_float(v.y << 16)          + b0.z, 0.f);
        At[k + 3][r] = fmaxf(__uint_as_float(v.y & 0xffff0000u)  + b0.w, 0.f);
        At[k + 4][r] = fmaxf(__uint_as_float(v.z << 16)          + b1.x, 0.f);
        At[k + 5][r] = fmaxf(__uint_as_float(v.z & 0xffff0000u)  + b1.y, 0.f);
        At[k + 6][r] = fmaxf(__uint_as_float(v.w << 16)          + b1.z, 0.f);
        At[k + 7][r] = fmaxf(__uint_as_float(v.w & 0xffff0000u)  + b1.w, 0.f);
    }
    __syncthreads();

    int tx = tid & 15, ty = tid >> 4;
    float acc[4][4] = {};
    #pragma unroll 8
    for (int k = 0; k < 64; ++k) {
        float4 wv = *(const float4*)&Ws[k][tx * 4];
        float4 av = *(const float4*)&At[k][ty * 4];
        acc[0][0] = fmaf(av.x, wv.x, acc[0][0]); acc[0][1] = fmaf(av.x, wv.y, acc[0][1]);
        acc[0][2] = fmaf(av.x, wv.z, acc[0][2]); acc[0][3] = fmaf(av.x, wv.w, acc[0][3]);
        acc[1][0] = fmaf(av.y, wv.x, acc[1][0]); acc[1][1] = fmaf(av.y, wv.y, acc[1][1]);
        acc[1][2] = fmaf(av.y, wv.z, acc[1][2]); acc[1][3] = fmaf(av.y, wv.w, acc[1][3]);
        acc[2][0] = fmaf(av.z, wv.x, acc[2][0]); acc[2][1] = fmaf(av.z, wv.y, acc[2][1]);
        acc[2][2] = fmaf(av.z, wv.z, acc[2][2]); acc[2][3] = fmaf(av.z, wv.w, acc[2][3]);
        acc[3][0] = fmaf(av.w, wv.x, acc[3][0]); acc[3][1] = fmaf(av.w, wv.y, acc[3][1]);
        acc[3][2] = fmaf(av.w, wv.z, acc[3][2]); acc[3][3] = fmaf(av.w, wv.w, acc[3][3]);
    }
    #pragma unroll
    for (int i = 0; i < 4; ++i) {
        int r = row0 + ty * 4 + i;
        if (r < N_NODES) {
            float d = dinv[r];
            ushort4 o;
            o.x = f2bf(acc[i][0] * d);
            o.y = f2bf(acc[i][1] * d);
            o.z = f2bf(acc[i][2] * d);
            o.w = f2bf(acc[i][3] * d);
            *(ushort4*)(out + (size_t)r * FEAT + tx * 4) = o;
        }
    }
}

// ---------------------------------------------------------------- gather aggregation: 2 nodes per wave
// 8 groups of 8 lanes; one uint4 load gathers 8 edges; both nodes' loads issue
// back-to-back -> 8 lines in flight per wave.
template <bool SRC_SCALED>
__global__ void k_gather(const ushort* __restrict__ h, const float* __restrict__ dinv,
                         const int* __restrict__ off, const int* __restrict__ csr_row,
                         ushort* __restrict__ out) {
    int tid = threadIdx.x;
    int lane = tid & 63;
    int pair = blockIdx.x * (blockDim.x >> 6) + (tid >> 6);
    int nodeA = pair * 2;
    int nodeB = nodeA + 1;
    if (nodeA >= N_NODES) return;
    bool hasB = (nodeB < N_NODES);
    int g = lane >> 3;          // group = which edge of the batch
    int sl = lane & 7;          // uint4 slot within the 128 B row
    int sA = off[nodeA], eA = off[nodeA + 1];
    int sB = hasB ? off[nodeB] : 0, eB = hasB ? off[nodeB + 1] : 0;
    float aA[8] = {}, aB[8] = {};

    // self-loop terms (group 0 handles A, group 1 handles B)
    if (g == 0) {
        uint4 v = ((const uint4*)(h + (size_t)nodeA * FEAT))[sl];
        acc8(aA, v, SRC_SCALED ? 1.0f : dinv[nodeA]);
    } else if (g == 1 && hasB) {
        uint4 v = ((const uint4*)(h + (size_t)nodeB * FEAT))[sl];
        acc8(aB, v, SRC_SCALED ? 1.0f : dinv[nodeB]);
    }

    int baseA = sA, baseB = sB;
    while (true) {                       // joint main loop: uniform branches
        bool dA = (baseA + 32 <= eA);
        bool dB = (baseB + 32 <= eB);
        if (!dA && !dB) break;
        int rA0, rA1, rA2, rA3, rB0, rB1, rB2, rB3;
        uint4 vA0, vA1, vA2, vA3, vB0, vB1, vB2, vB3;
        float wA0, wA1, wA2, wA3, wB0, wB1, wB2, wB3;
        if (dA) {
            rA0 = csr_row[baseA + g];      rA1 = csr_row[baseA + 8 + g];
            rA2 = csr_row[baseA + 16 + g]; rA3 = csr_row[baseA + 24 + g];
            vA0 = ((const uint4*)(h + (size_t)rA0 * FEAT))[sl];
            vA1 = ((const uint4*)(h + (size_t)rA1 * FEAT))[sl];
            vA2 = ((const uint4*)(h + (size_t)rA2 * FEAT))[sl];
            vA3 = ((const uint4*)(h + (size_t)rA3 * FEAT))[sl];
            wA0 = SRC_SCALED ? 1.0f : dinv[rA0]; wA1 = SRC_SCALED ? 1.0f : dinv[rA1];
            wA2 = SRC_SCALED ? 1.0f : dinv[rA2]; wA3 = SRC_SCALED ? 1.0f : dinv[rA3];
        }
        if (dB) {
            rB0 = csr_row[baseB + g];      rB1 = csr_row[baseB + 8 + g];
            rB2 = csr_row[baseB + 16 + g]; rB3 = csr_row[baseB + 24 + g];
            vB0 = ((const uint4*)(h + (size_t)rB0 * FEAT))[sl];
            vB1 = ((const uint4*)(h + (size_t)rB1 * FEAT))[sl];
            vB2 = ((const uint4*)(h + (size_t)rB2 * FEAT))[sl];
            vB3 = ((const uint4*)(h + (size_t)rB3 * FEAT))[sl];
            wB0 = SRC_SCALED ? 1.0f : dinv[rB0]; wB1 = SRC_SCALED ? 1.0f : dinv[rB1];
            wB2 = SRC_SCALED ? 1.0f : dinv[rB2]; wB3 = SRC_SCALED ? 1.0f : dinv[rB3];
        }
        if (dA) {
            acc8(aA, vA0, wA0); acc8(aA, vA1, wA1);
            acc8(aA, vA2, wA2); acc8(aA, vA3, wA3);
            baseA += 32;
        }
        if (dB) {
            acc8(aB, vB0, wB0); acc8(aB, vB1, wB1);
            acc8(aB, vB2, wB2); acc8(aB, vB3, wB3);
            baseB += 32;
        }
    }
    // drain A
    if (baseA + 16 <= eA) {
        int r0 = csr_row[baseA + g], r1 = csr_row[baseA + 8 + g];
        uint4 v0 = ((const uint4*)(h + (size_t)r0 * FEAT))[sl];
        uint4 v1 = ((const uint4*)(h + (size_t)r1 * FEAT))[sl];
        acc8(aA, v0, SRC_SCALED ? 1.0f : dinv[r0]);
        acc8(aA, v1, SRC_SCALED ? 1.0f : dinv[r1]);
        baseA += 16;
    }
    for (; baseA < eA; baseA += 8) {
        int ei = baseA + g;
        if (ei < eA) {
            int r = csr_row[ei];
            uint4 v = ((const uint4*)(h + (size_t)r * FEAT))[sl];
            acc8(aA, v, SRC_SCALED ? 1.0f : dinv[r]);
        }
    }
    // drain B
    if (hasB) {
        if (baseB + 16 <= eB) {
            int r0 = csr_row[baseB + g], r1 = csr_row[baseB + 8 + g];
            uint4 v0 = ((const uint4*)(h + (size_t)r0 * FEAT))[sl];
            uint4 v1 = ((const uint4*)(h + (size_t)r1 * FEAT))[sl];
            acc8(aB, v0, SRC_SCALED ? 1.0f : dinv[r0]);
            acc8(aB, v1, SRC_SCALED ? 1.0f : dinv[r1]);
            baseB += 16;
        }
        for (; baseB < eB; baseB += 8) {
            int ei = baseB + g;
            if (ei < eB) {
                int r = csr_row[ei];
                uint4 v = ((const uint4*)(h + (size_t)r * FEAT))[sl];
                acc8(aB, v, SRC_SCALED ? 1.0f : dinv[r]);
            }
        }
    }
    // butterfly reduction across groups: every lane ends with the full sum for its sl
    #pragma unroll
    for (int j = 0; j < 8; ++j) {
        aA[j] += __shfl_xor(aA[j], 8); aA[j] += __shfl_xor(aA[j], 16); aA[j] += __shfl_xor(aA[j], 32);
        aB[j] += __shfl_xor(aB[j], 8); aB[j] += __shfl_xor(aB[j], 16); aB[j] += __shfl_xor(aB[j], 32);
    }
    if (g == 0) {
        float d = dinv[nodeA];
        uint4 o;
        o.x = (unsigned)f2bf(aA[0] * d) | ((unsigned)f2bf(aA[1] * d) << 16);
        o.y = (unsigned)f2bf(aA[2] * d) | ((unsigned)f2bf(aA[3] * d) << 16);
        o.z = (unsigned)f2bf(aA[4] * d) | ((unsigned)f2bf(aA[5] * d) << 16);
        o.w = (unsigned)f2bf(aA[6] * d) | ((unsigned)f2bf(aA[7] * d) << 16);
        ((uint4*)(out + (size_t)nodeA * FEAT))[sl] = o;
    } else if (g == 1 && hasB) {
        float d = dinv[nodeB];
        uint4 o;
        o.x = (unsigned)f2bf(aB[0] * d) | ((unsigned)f2bf(aB[1] * d) << 16);
        o.y = (unsigned)f2bf(aB[2] * d) | ((unsigned)f2bf(aB[3] * d) << 16);
        o.z = (unsigned)f2bf(aB[4] * d) | ((unsigned)f2bf(aB[5] * d) << 16);
        o.w = (unsigned)f2bf(aB[6] * d) | ((unsigned)f2bf(aB[7] * d) << 16);
        ((uint4*)(out + (size_t)nodeB * FEAT))[sl] = o;
    }
}

// ---------------------------------------------------------------- mean pool (64 nodes/block, bf16 in)
__global__ void k_pool(const ushort* __restrict__ agg, const float* __restrict__ b2,
                       const int* __restrict__ batch, float* sums, float* cnts) {
    const int NPB = 64;
    int f = threadIdx.x;
    int start = blockIdx.x * NPB;
    if (start >= N_NODES) return;
    int end = min(start + NPB, N_NODES);
    float bias = b2[f];
    int gcur = batch[start];
    float acc = 0.0f, cacc = 0.0f;
    for (int n = start; n < end; ++n) {
        int g = batch[n];
        if (g != gcur) {
            atomicAdd(&sums[gcur * FEAT + f], acc);
            if (f == 0) atomicAdd(&cnts[gcur], cacc);
            acc = 0.0f; cacc = 0.0f; gcur = g;
        }
        float v = bf2f(agg[(size_t)n * FEAT + f]) + bias;
        acc += fmaxf(v, 0.0f);
        cacc += 1.0f;
    }
    atomicAdd(&sums[gcur * FEAT + f], acc);
    if (f == 0) atomicAdd(&cnts[gcur], cacc);
}

__global__ void k_final(const float* __restrict__ sums, const float* __restrict__ cnts,
                        float* __restrict__ out) {
    int i = blockIdx.x * blockDim.x + threadIdx.x;
    if (i < N_GRAPHS * FEAT) out[i] = sums[i] / fmaxf(cnts[i >> 6], 1.0f);
}

// ---------------------------------------------------------------- launch
extern "C" void kernel_launch(void* const* d_in, const int* in_sizes, int n_in,
                              void* d_out, int out_size, void* d_ws, size_t ws_size,
                              hipStream_t stream) {
    const float* x     = (const float*)d_in[0];
    const int*   ei    = (const int*)d_in[1];
    const int*   batch = (const int*)d_in[2];
    const float* W1    = (const float*)d_in[3];
    const float* b1    = (const float*)d_in[4];
    const float* W2    = (const float*)d_in[5];
    const float* b2    = (const float*)d_in[6];
    const int* row = ei;
    const int* col = ei + N_EDGES;

    size_t o = 0;
    auto alloc = [&](size_t bytes) { size_t cur = o; o = (o + bytes + 255) & ~(size_t)255; return cur; };
    char* ws = (char*)d_ws;
    float*  dinv    = (float*) (ws + alloc(N_NODES * 4));
    int*    offs    = (int*)   (ws + alloc((N_NODES + 1) * 4));
    int*    bcnt    = (int*)   (ws + alloc(NBKT * 4));
    float*  pool    = (float*) (ws + alloc((N_GRAPHS * FEAT + N_GRAPHS) * 4));
    ushort* hbf     = (ushort*)(ws + alloc((size_t)N_NODES * FEAT * 2));   // bf16 h'
    ushort* aggA    = (ushort*)(ws + alloc((size_t)N_NODES * FEAT * 2));   // bf16 agg1
    ushort* aggB    = (ushort*)(ws + alloc((size_t)N_NODES * FEAT * 2));   // bf16 agg2
    int*    csr_row = (int*)   (ws + alloc((size_t)N_EDGES * 4));
    int*    tmp     = (int*)   (ws + alloc((size_t)NBKT * BKT_PAD * 4));   // 14.0 MB sort staging
    float* psum = pool;
    float* pcnt = pool + N_GRAPHS * FEAT;

    const int B = 256;
    hipLaunchKernelGGL(k_zero, dim3(17), dim3(B), 0, stream, bcnt, pool, offs);
    // bucket || gemm1 (h1 = x@W1, unscaled; dinv not ready yet)
    hipLaunchKernelGGL(k_pre, dim3(196 + GEMM1_BLKS), dim3(1024), 0, stream,
                       row, col, bcnt, tmp, x, W1, hbf);
    hipLaunchKernelGGL(k_build, dim3(NBKT), dim3(1024), 0, stream, tmp, bcnt, offs, dinv, csr_row);

    // layer 1 aggregate: agg1[c] = dinv[c]*(h1[c]*dinv[c] + sum h1[r]*dinv[r])
    hipLaunchKernelGGL((k_gather<false>), dim3((N_NODES / 2 + 3) / 4), dim3(B), 0, stream,
                       hbf, dinv, offs, csr_row, aggA);
    // layer 2: h2' = relu(agg1 + b1) @ W2 * dinv (bf16); agg2 = gather (pre-scaled)
    hipLaunchKernelGGL(k_gemm2, dim3((N_NODES + 63) / 64), dim3(B), 0, stream, aggA, W2, b1, dinv, hbf);
    hipLaunchKernelGGL((k_gather<true>), dim3((N_NODES / 2 + 3) / 4), dim3(B), 0, stream,
                       hbf, dinv, offs, csr_row, aggB);

    hipLaunchKernelGGL(k_pool, dim3((N_NODES + 63) / 64), dim3(64), 0, stream, aggB, b2, batch, psum, pcnt);
    hipLaunchKernelGGL(k_final, dim3(16), dim3(B), 0, stream, psum, pcnt, (float*)d_out);
}

// Round 13
// 233.734 us; speedup vs baseline: 1.0859x; 1.0859x over previous
//
#include <hip/hip_runtime.h>

#define N_NODES 100000
#define N_EDGES 3200000
#define FEAT 64
#define N_GRAPHS 64

#define BKT_SHIFT 8
#define BKT_SIZE  256                       // nodes per bucket
#define NBKT      391                       // ceil(N_NODES / 256)
#define BKT_PAD   8960                      // mean 8184, sd 90 -> mean + 8.6 sigma
#define E4        (N_EDGES / 4)             // 800000 int4 chunks
#define GEMM1_BLKS ((N_NODES + 63) / 64)    // 1563

__device__ __forceinline__ ushort f2bf(float f) {      // round-to-nearest-even
    unsigned u = __float_as_uint(f);
    return (ushort)((u + 0x7fffu + ((u >> 16) & 1u)) >> 16);
}
__device__ __forceinline__ float bf2f(ushort s) {
    return __uint_as_float(((unsigned)s) << 16);
}

// ---------------------------------------------------------------- zero
__global__ void k_zero(int* __restrict__ bcnt, float* __restrict__ pool, int* __restrict__ offs) {
    int i = blockIdx.x * blockDim.x + threadIdx.x;
    if (i < NBKT) bcnt[i] = 0;
    if (i < N_GRAPHS * FEAT + N_GRAPHS) pool[i] = 0.0f;
    if (i == 0) offs[N_NODES] = N_EDGES;
}

// ---------------------------------------------------------------- fused: bucket (blocks 0..195) | gemm1 (rest)
__global__ void __launch_bounds__(1024) k_pre(const int* __restrict__ row,
                                              const int* __restrict__ col,
                                              int* __restrict__ bcnt,
                                              int* __restrict__ tmp,
                                              const float* __restrict__ x,
                                              const float* __restrict__ W1,
                                              ushort* __restrict__ hbf) {
    __shared__ int lcnt0[NBKT];
    __shared__ int lcnt1[NBKT];             // 2x replicated histogram halves contention
    __shared__ float Ws[64][64];
    __shared__ float At[64][68];
    int tid = threadIdx.x;

    if (blockIdx.x < 196) {
        // ---------------- bucket path ----------------
        int* lc = (tid >= 512) ? lcnt1 : lcnt0;
        if (tid < NBKT) { lcnt0[tid] = 0; lcnt1[tid] = 0; }
        __syncthreads();
        int base = blockIdx.x * 4096;           // int4 units; 16 edges/thread
        int4 c[4];
        #pragma unroll
        for (int k = 0; k < 4; ++k) {
            int t4 = base + k * 1024 + tid;
            if (t4 < E4) {
                c[k] = ((const int4*)col)[t4];
                atomicAdd(&lc[c[k].x >> BKT_SHIFT], 1);
                atomicAdd(&lc[c[k].y >> BKT_SHIFT], 1);
                atomicAdd(&lc[c[k].z >> BKT_SHIFT], 1);
                atomicAdd(&lc[c[k].w >> BKT_SHIFT], 1);
            }
        }
        __syncthreads();
        if (tid < NBKT) {
            int l0 = lcnt0[tid], l1 = lcnt1[tid];
            int bse = atomicAdd(&bcnt[tid], l0 + l1);
            lcnt0[tid] = bse;               // cursor for copy 0
            lcnt1[tid] = bse + l0;          // cursor for copy 1
        }
        __syncthreads();
        #pragma unroll
        for (int k = 0; k < 4; ++k) {
            int t4 = base + k * 1024 + tid;
            if (t4 < E4) {
                int4 r = ((const int4*)row)[t4];
                int b0 = c[k].x >> BKT_SHIFT, b1 = c[k].y >> BKT_SHIFT;
                int b2 = c[k].z >> BKT_SHIFT, b3 = c[k].w >> BKT_SHIFT;
                int s0 = atomicAdd(&lc[b0], 1);
                int s1 = atomicAdd(&lc[b1], 1);
                int s2 = atomicAdd(&lc[b2], 1);
                int s3 = atomicAdd(&lc[b3], 1);
                if (s0 < BKT_PAD) tmp[b0 * BKT_PAD + s0] = (r.x << BKT_SHIFT) | (c[k].x & (BKT_SIZE - 1));
                if (s1 < BKT_PAD) tmp[b1 * BKT_PAD + s1] = (r.y << BKT_SHIFT) | (c[k].y & (BKT_SIZE - 1));
                if (s2 < BKT_PAD) tmp[b2 * BKT_PAD + s2] = (r.z << BKT_SHIFT) | (c[k].z & (BKT_SIZE - 1));
                if (s3 < BKT_PAD) tmp[b3 * BKT_PAD + s3] = (r.w << BKT_SHIFT) | (c[k].w & (BKT_SIZE - 1));
            }
        }
    } else {
        // ---------------- gemm1 path: h = x @ W1 (UNSCALED; dinv folded into gather) ----------------
        int row0 = (blockIdx.x - 196) * 64;
        {
            float4 v = ((const float4*)W1)[tid];
            *(float4*)&Ws[tid >> 4][(tid & 15) * 4] = v;
        }
        {
            int r = tid >> 4, f4 = tid & 15;
            int grow = row0 + r;
            float4 v = make_float4(0.f, 0.f, 0.f, 0.f);
            if (grow < N_NODES) v = ((const float4*)(x + (size_t)grow * FEAT))[f4];
            int k = f4 * 4;
            At[k][r] = v.x; At[k + 1][r] = v.y; At[k + 2][r] = v.z; At[k + 3][r] = v.w;
        }
        __syncthreads();
        int tx = tid & 31, ty = tid >> 5;       // 32x32 threads; 2x2 each
        float a00 = 0.f, a01 = 0.f, a10 = 0.f, a11 = 0.f;
        #pragma unroll 8
        for (int k = 0; k < 64; ++k) {
            float2 wv = *(const float2*)&Ws[k][tx * 2];
            float2 av = *(const float2*)&At[k][ty * 2];
            a00 = fmaf(av.x, wv.x, a00); a01 = fmaf(av.x, wv.y, a01);
            a10 = fmaf(av.y, wv.x, a10); a11 = fmaf(av.y, wv.y, a11);
        }
        int r0 = row0 + ty * 2;
        if (r0 < N_NODES)
            *(unsigned*)(hbf + (size_t)r0 * FEAT + tx * 2) =
                (unsigned)f2bf(a00) | ((unsigned)f2bf(a01) << 16);
        if (r0 + 1 < N_NODES)
            *(unsigned*)(hbf + (size_t)(r0 + 1) * FEAT + tx * 2) =
                (unsigned)f2bf(a10) | ((unsigned)f2bf(a11) << 16);
    }
}

// ---------------------------------------------------------------- per-bucket CSR build (register-staged)
__global__ void __launch_bounds__(1024) k_build(const int* __restrict__ tmp,
                                                const int* __restrict__ bcnt,
                                                int* __restrict__ offs,
                                                float* __restrict__ dinv,
                                                int* __restrict__ csr_row) {
    __shared__ int hist[BKT_SIZE];
    __shared__ int wpart[4];
    __shared__ int sh_start;
    int b = blockIdx.x, tid = threadIdx.x;

    if (tid < 64) {
        int sum = 0;
        for (int c = 0; c < NBKT; c += 64) {
            int idx = c + tid;
            int v = (idx < b) ? bcnt[idx] : 0;
            #pragma unroll
            for (int d2 = 1; d2 < 64; d2 <<= 1) v += __shfl_xor(v, d2);
            sum += v;
        }
        if (tid == 0) sh_start = sum;
    }
    if (tid < BKT_SIZE) hist[tid] = 0;
    __syncthreads();
    int s = sh_start;
    int count = min(bcnt[b], BKT_PAD);
    const int* seg = tmp + (size_t)b * BKT_PAD;

    int e[9];
    #pragma unroll
    for (int k = 0; k < 9; ++k) {
        int idx = k * 1024 + tid;
        e[k] = -1;
        if (idx < count) {
            e[k] = seg[idx];
            atomicAdd(&hist[e[k] & (BKT_SIZE - 1)], 1);
        }
    }
    __syncthreads();

    int cnt_n = 0, p = 0;
    if (tid < BKT_SIZE) {
        cnt_n = hist[tid];
        p = cnt_n;
        #pragma unroll
        for (int d = 1; d < 64; d <<= 1) {
            int t2 = __shfl_up(p, d);
            if ((tid & 63) >= d) p += t2;
        }
        if ((tid & 63) == 63) wpart[tid >> 6] = p;
    }
    __syncthreads();
    if (tid == 0) {
        int run = 0;
        #pragma unroll
        for (int w = 0; w < 4; ++w) { int t2 = wpart[w]; wpart[w] = run; run += t2; }
    }
    __syncthreads();
    if (tid < BKT_SIZE) {
        int excl = wpart[tid >> 6] + p - cnt_n;
        int node = (b << BKT_SHIFT) + tid;
        if (node < N_NODES) {
            offs[node] = s + excl;
            dinv[node] = rsqrtf((float)(cnt_n + 1));   // +1 self-loop
        }
        hist[tid] = s + excl;                           // reuse as cursor
    }
    __syncthreads();

    #pragma unroll
    for (int k = 0; k < 9; ++k) {
        if (e[k] >= 0) {
            int slot = atomicAdd(&hist[e[k] & (BKT_SIZE - 1)], 1);
            csr_row[slot] = e[k] >> BKT_SHIFT;
        }
    }
}

// ---------------------------------------------------------------- tiled GEMM layer2: bf16 agg in, relu(in+bias)
__global__ void __launch_bounds__(256, 4) k_gemm2(const ushort* __restrict__ in,
                                                  const float* __restrict__ W,
                                                  const float* __restrict__ bias,
                                                  const float* __restrict__ dinv,
                                                  ushort* __restrict__ out) {
    __shared__ float Ws[64][64];
    __shared__ float At[64][68];
    int tid = threadIdx.x;
    int row0 = blockIdx.x * 64;

    const float4* Wv = (const float4*)W;
    #pragma unroll
    for (int i = 0; i < 4; ++i) {
        int idx = tid + i * 256;
        float4 v = Wv[idx];
        *(float4*)&Ws[idx >> 4][(idx & 15) * 4] = v;
    }
    #pragma unroll
    for (int i = 0; i < 2; ++i) {
        int idx = tid + i * 256;            // uint4 index (8 bf16), 512 total
        int r = idx >> 3, q = idx & 7;
        int grow = row0 + r;
        uint4 v = make_uint4(0u, 0u, 0u, 0u);
        if (grow < N_NODES) v = ((const uint4*)(in + (size_t)grow * FEAT))[q];
        float4 b0 = ((const float4*)bias)[q * 2];
        float4 b1 = ((const float4*)bias)[q * 2 + 1];
        int k = q * 8;
        At[k + 0][r] = fmaxf(__uint_as_float(v.x << 16)          + b0.x, 0.f);
        At[k + 1][r] = fmaxf(__uint_as_float(v.x & 0xffff0000u)  + b0.y, 0.f);
        At[k + 2][r] = fmaxf(__uint_as_float(v.y << 16)          + b0.z, 0.f);
        At[k + 3][r] = fmaxf(__uint_as_float(v.y & 0xffff0000u)  + b0.w, 0.f);
        At[k + 4][r] = fmaxf(__uint_as_float(v.z << 16)          + b1.x, 0.f);
        At[k + 5][r] = fmaxf(__uint_as_float(v.z & 0xffff0000u)  + b1.y, 0.f);
        At[k + 6][r] = fmaxf(__uint_as_float(v.w << 16)          + b1.z, 0.f);
        At[k + 7][r] = fmaxf(__uint_as_float(v.w & 0xffff0000u)  + b1.w, 0.f);
    }
    __syncthreads();

    int tx = tid & 15, ty = tid >> 4;
    float acc[4][4] = {};
    #pragma unroll 8
    for (int k = 0; k < 64; ++k) {
        float4 wv = *(const float4*)&Ws[k][tx * 4];
        float4 av = *(const float4*)&At[k][ty * 4];
        acc[0][0] = fmaf(av.x, wv.x, acc[0][0]); acc[0][1] = fmaf(av.x, wv.y, acc[0][1]);
        acc[0][2] = fmaf(av.x, wv.z, acc[0][2]); acc[0][3] = fmaf(av.x, wv.w, acc[0][3]);
        acc[1][0] = fmaf(av.y, wv.x, acc[1][0]); acc[1][1] = fmaf(av.y, wv.y, acc[1][1]);
        acc[1][2] = fmaf(av.y, wv.z, acc[1][2]); acc[1][3] = fmaf(av.y, wv.w, acc[1][3]);
        acc[2][0] = fmaf(av.z, wv.x, acc[2][0]); acc[2][1] = fmaf(av.z, wv.y, acc[2][1]);
        acc[2][2] = fmaf(av.z, wv.z, acc[2][2]); acc[2][3] = fmaf(av.z, wv.w, acc[2][3]);
        acc[3][0] = fmaf(av.w, wv.x, acc[3][0]); acc[3][1] = fmaf(av.w, wv.y, acc[3][1]);
        acc[3][2] = fmaf(av.w, wv.z, acc[3][2]); acc[3][3] = fmaf(av.w, wv.w, acc[3][3]);
    }
    #pragma unroll
    for (int i = 0; i < 4; ++i) {
        int r = row0 + ty * 4 + i;
        if (r < N_NODES) {
            float d = dinv[r];
            ushort4 o;
            o.x = f2bf(acc[i][0] * d);
            o.y = f2bf(acc[i][1] * d);
            o.z = f2bf(acc[i][2] * d);
            o.w = f2bf(acc[i][3] * d);
            *(ushort4*)(out + (size_t)r * FEAT + tx * 4) = o;
        }
    }
}

// ---------------------------------------------------------------- gather aggregation (round-11 version)
// wave = 1 node; 8 groups of 8 lanes; one uint4 load gathers 8 edges.
// SRC_SCALED: if false, h rows are unscaled -> multiply each gathered row by dinv[src]
template <bool SRC_SCALED>
__global__ void k_gather(const ushort* __restrict__ h, const float* __restrict__ dinv,
                         const int* __restrict__ off, const int* __restrict__ csr_row,
                         ushort* __restrict__ out) {
    int tid = threadIdx.x;
    int lane = tid & 63;
    int node = blockIdx.x * (blockDim.x >> 6) + (tid >> 6);
    if (node >= N_NODES) return;
    int g = lane >> 3;          // group = which edge of the batch
    int sl = lane & 7;          // uint4 slot within the 128 B row
    int s = off[node], e = off[node + 1];
    float a0 = 0.f, a1 = 0.f, a2 = 0.f, a3 = 0.f, a4 = 0.f, a5 = 0.f, a6 = 0.f, a7 = 0.f;

#define ACC8(vv, wt) do {                                           \
        a0 = fmaf(__uint_as_float((vv).x << 16),         wt, a0);   \
        a1 = fmaf(__uint_as_float((vv).x & 0xffff0000u), wt, a1);   \
        a2 = fmaf(__uint_as_float((vv).y << 16),         wt, a2);   \
        a3 = fmaf(__uint_as_float((vv).y & 0xffff0000u), wt, a3);   \
        a4 = fmaf(__uint_as_float((vv).z << 16),         wt, a4);   \
        a5 = fmaf(__uint_as_float((vv).z & 0xffff0000u), wt, a5);   \
        a6 = fmaf(__uint_as_float((vv).w << 16),         wt, a6);   \
        a7 = fmaf(__uint_as_float((vv).w & 0xffff0000u), wt, a7);   \
    } while (0)

    float selfw = SRC_SCALED ? 1.0f : dinv[node];
    if (g == 0) {                                            // self-loop term
        uint4 v = ((const uint4*)(h + (size_t)node * FEAT))[sl];
        ACC8(v, selfw);
    }
    int base = s;
    for (; base + 32 <= e; base += 32) {                     // 32 edges/iter
        int r0 = csr_row[base + g];
        int r1 = csr_row[base + 8 + g];
        int r2 = csr_row[base + 16 + g];
        int r3 = csr_row[base + 24 + g];
        float w0 = SRC_SCALED ? 1.0f : dinv[r0];
        float w1 = SRC_SCALED ? 1.0f : dinv[r1];
        float w2 = SRC_SCALED ? 1.0f : dinv[r2];
        float w3 = SRC_SCALED ? 1.0f : dinv[r3];
        uint4 v0 = ((const uint4*)(h + (size_t)r0 * FEAT))[sl];
        uint4 v1 = ((const uint4*)(h + (size_t)r1 * FEAT))[sl];
        uint4 v2 = ((const uint4*)(h + (size_t)r2 * FEAT))[sl];
        uint4 v3 = ((const uint4*)(h + (size_t)r3 * FEAT))[sl];
        ACC8(v0, w0); ACC8(v1, w1); ACC8(v2, w2); ACC8(v3, w3);
    }
    if (base + 16 <= e) {                                    // 16-edge step
        int r0 = csr_row[base + g];
        int r1 = csr_row[base + 8 + g];
        float w0 = SRC_SCALED ? 1.0f : dinv[r0];
        float w1 = SRC_SCALED ? 1.0f : dinv[r1];
        uint4 v0 = ((const uint4*)(h + (size_t)r0 * FEAT))[sl];
        uint4 v1 = ((const uint4*)(h + (size_t)r1 * FEAT))[sl];
        ACC8(v0, w0); ACC8(v1, w1);
        base += 16;
    }
    for (; base < e; base += 8) {                            // tail: 8 edges/iter
        int ei = base + g;
        if (ei < e) {
            int r = csr_row[ei];
            float wt = SRC_SCALED ? 1.0f : dinv[r];
            uint4 v = ((const uint4*)(h + (size_t)r * FEAT))[sl];
            ACC8(v, wt);
        }
    }
#undef ACC8
#define RED(a) a += __shfl_xor(a, 8); a += __shfl_xor(a, 16); a += __shfl_xor(a, 32);
    RED(a0) RED(a1) RED(a2) RED(a3) RED(a4) RED(a5) RED(a6) RED(a7)
#undef RED
    if (g == 0) {
        float d = dinv[node];
        uint4 o;
        o.x = (unsigned)f2bf(a0 * d) | ((unsigned)f2bf(a1 * d) << 16);
        o.y = (unsigned)f2bf(a2 * d) | ((unsigned)f2bf(a3 * d) << 16);
        o.z = (unsigned)f2bf(a4 * d) | ((unsigned)f2bf(a5 * d) << 16);
        o.w = (unsigned)f2bf(a6 * d) | ((unsigned)f2bf(a7 * d) << 16);
        ((uint4*)(out + (size_t)node * FEAT))[sl] = o;
    }
}

// ---------------------------------------------------------------- mean pool (64 nodes/block, bf16 in)
__global__ void k_pool(const ushort* __restrict__ agg, const float* __restrict__ b2,
                       const int* __restrict__ batch, float* sums, float* cnts) {
    const int NPB = 64;
    int f = threadIdx.x;
    int start = blockIdx.x * NPB;
    if (start >= N_NODES) return;
    int end = min(start + NPB, N_NODES);
    float bias = b2[f];
    int gcur = batch[start];
    float acc = 0.0f, cacc = 0.0f;
    for (int n = start; n < end; ++n) {
        int g = batch[n];
        if (g != gcur) {
            atomicAdd(&sums[gcur * FEAT + f], acc);
            if (f == 0) atomicAdd(&cnts[gcur], cacc);
            acc = 0.0f; cacc = 0.0f; gcur = g;
        }
        float v = bf2f(agg[(size_t)n * FEAT + f]) + bias;
        acc += fmaxf(v, 0.0f);
        cacc += 1.0f;
    }
    atomicAdd(&sums[gcur * FEAT + f], acc);
    if (f == 0) atomicAdd(&cnts[gcur], cacc);
}

__global__ void k_final(const float* __restrict__ sums, const float* __restrict__ cnts,
                        float* __restrict__ out) {
    int i = blockIdx.x * blockDim.x + threadIdx.x;
    if (i < N_GRAPHS * FEAT) out[i] = sums[i] / fmaxf(cnts[i >> 6], 1.0f);
}

// ---------------------------------------------------------------- launch
extern "C" void kernel_launch(void* const* d_in, const int* in_sizes, int n_in,
                              void* d_out, int out_size, void* d_ws, size_t ws_size,
                              hipStream_t stream) {
    const float* x     = (const float*)d_in[0];
    const int*   ei    = (const int*)d_in[1];
    const int*   batch = (const int*)d_in[2];
    const float* W1    = (const float*)d_in[3];
    const float* b1    = (const float*)d_in[4];
    const float* W2    = (const float*)d_in[5];
    const float* b2    = (const float*)d_in[6];
    const int* row = ei;
    const int* col = ei + N_EDGES;

    size_t o = 0;
    auto alloc = [&](size_t bytes) { size_t cur = o; o = (o + bytes + 255) & ~(size_t)255; return cur; };
    char* ws = (char*)d_ws;
    float*  dinv    = (float*) (ws + alloc(N_NODES * 4));
    int*    offs    = (int*)   (ws + alloc((N_NODES + 1) * 4));
    int*    bcnt    = (int*)   (ws + alloc(NBKT * 4));
    float*  pool    = (float*) (ws + alloc((N_GRAPHS * FEAT + N_GRAPHS) * 4));
    ushort* hbf     = (ushort*)(ws + alloc((size_t)N_NODES * FEAT * 2));   // bf16 h'
    ushort* aggA    = (ushort*)(ws + alloc((size_t)N_NODES * FEAT * 2));   // bf16 agg1
    ushort* aggB    = (ushort*)(ws + alloc((size_t)N_NODES * FEAT * 2));   // bf16 agg2
    int*    csr_row = (int*)   (ws + alloc((size_t)N_EDGES * 4));
    int*    tmp     = (int*)   (ws + alloc((size_t)NBKT * BKT_PAD * 4));   // 14.0 MB sort staging
    float* psum = pool;
    float* pcnt = pool + N_GRAPHS * FEAT;

    const int B = 256;
    hipLaunchKernelGGL(k_zero, dim3(17), dim3(B), 0, stream, bcnt, pool, offs);
    // bucket || gemm1 (h1 = x@W1, unscaled; dinv not ready yet)
    hipLaunchKernelGGL(k_pre, dim3(196 + GEMM1_BLKS), dim3(1024), 0, stream,
                       row, col, bcnt, tmp, x, W1, hbf);
    hipLaunchKernelGGL(k_build, dim3(NBKT), dim3(1024), 0, stream, tmp, bcnt, offs, dinv, csr_row);

    // layer 1 aggregate: agg1[c] = dinv[c]*(h1[c]*dinv[c] + sum h1[r]*dinv[r])
    hipLaunchKernelGGL((k_gather<false>), dim3((N_NODES + 3) / 4), dim3(B), 0, stream,
                       hbf, dinv, offs, csr_row, aggA);
    // layer 2: h2' = relu(agg1 + b1) @ W2 * dinv (bf16); agg2 = gather (pre-scaled)
    hipLaunchKernelGGL(k_gemm2, dim3((N_NODES + 63) / 64), dim3(B), 0, stream, aggA, W2, b1, dinv, hbf);
    hipLaunchKernelGGL((k_gather<true>), dim3((N_NODES + 3) / 4), dim3(B), 0, stream,
                       hbf, dinv, offs, csr_row, aggB);

    hipLaunchKernelGGL(k_pool, dim3((N_NODES + 63) / 64), dim3(64), 0, stream, aggB, b2, batch, psum, pcnt);
    hipLaunchKernelGGL(k_final, dim3(16), dim3(B), 0, stream, psum, pcnt, (float*)d_out);
}